// Round 1
// baseline (574.814 us; speedup 1.0000x reference)
//
#include <hip/hip_runtime.h>
#include <hip/hip_bf16.h>

typedef __attribute__((ext_vector_type(8))) short short8;
typedef __attribute__((ext_vector_type(4))) float f32x4;

#define NROWS 32768
#define CDIM 1024
#define BNC 256
#define TOPK 128

struct alignas(8) U4 { unsigned short x, y, z, w; };

__device__ __forceinline__ unsigned short f2bf(float f){
  union { float f; unsigned u; } v; v.f = f;
  unsigned r = v.u + 0x7FFFu + ((v.u >> 16) & 1u);
  return (unsigned short)(r >> 16);
}
__device__ __forceinline__ float bf2f(unsigned short h){
  union { unsigned u; float f; } v; v.u = ((unsigned)h) << 16;
  return v.f;
}
__device__ __forceinline__ void gl16(const void* g, void* l){
  __builtin_amdgcn_global_load_lds((const __attribute__((address_space(1))) void*)g,
                                   (__attribute__((address_space(3))) void*)l, 16, 0, 0);
}
// XOR swizzle within a [128 rows][64 bytes] tile: flip 16B-granule index by row&3
__device__ __forceinline__ int swz(int o){ return o ^ (((o >> 6) & 3) << 4); }

// stage one [128 rows][32 k] bf16 tile (8 KB) into LDS (linear dest, pre-swizzled src)
__device__ __forceinline__ void stage_tile(const unsigned short* g0, int gstride,
                                           char* lds, int tid){
  #pragma unroll
  for (int i = 0; i < 2; ++i){
    int o = tid * 16 + i * 4096;
    int lb = swz(o);
    gl16((const char*)g0 + (lb >> 6) * gstride + (lb & 63), lds + o);
  }
}
// load MFMA A/B fragment: lane provides row ridx, k-granule (lane>>4), swizzled read
__device__ __forceinline__ short8 frag_ld(const char* lds, int ridx, int lane){
  int o = ridx * 64 + (((lane >> 4) ^ (ridx & 3)) << 4);
  return *(const short8*)(lds + o);
}

// ---------------- param prep ----------------
__global__ void k_wt(const float* __restrict__ W, unsigned short* __restrict__ Wt){
  __shared__ float t[32][33];
  int tx = threadIdx.x, ty = threadIdx.y;
  int bx = blockIdx.x * 32, by = blockIdx.y * 32;
  for (int i = ty; i < 32; i += 8)
    t[i][tx] = W[(by + i) * CDIM + bx + tx];
  __syncthreads();
  for (int i = ty; i < 32; i += 8)
    Wt[(bx + i) * CDIM + by + tx] = f2bf(t[tx][i]);
}

__global__ void k_split(const float* __restrict__ s, unsigned short* __restrict__ h,
                        unsigned short* __restrict__ l, int n){
  int i = blockIdx.x * 256 + threadIdx.x;
  if (i < n){
    float f = s[i];
    unsigned short hh = f2bf(f);
    h[i] = hh; l[i] = f2bf(f - bf2f(hh));
  }
}

// ---------------- bottleneck: grouped conv + BN + GELU, plus x->bf16 ----------------
__global__ __launch_bounds__(256) void k_bottleneck(
    const float* __restrict__ x,
    const float* __restrict__ cwo, const float* __restrict__ cbo,
    const float* __restrict__ go,  const float* __restrict__ bto,
    const float* __restrict__ mo,  const float* __restrict__ vo,
    const float* __restrict__ cwi, const float* __restrict__ cbi,
    const float* __restrict__ gi,  const float* __restrict__ bti,
    const float* __restrict__ mi,  const float* __restrict__ vi,
    unsigned short* __restrict__ xbf,
    unsigned short* __restrict__ uho, unsigned short* __restrict__ ulo,
    unsigned short* __restrict__ uhi, unsigned short* __restrict__ uli)
{
  const int t = threadIdx.x;
  const int r0 = blockIdx.x * 8;
  float4 cwov = ((const float4*)cwo)[t];
  float4 cwiv = ((const float4*)cwi)[t];
  float sco = go[t] * rsqrtf(vo[t] + 1e-5f);
  float sho = bto[t] - mo[t] * sco;
  float cbov = cbo[t];
  float sci = gi[t] * rsqrtf(vi[t] + 1e-5f);
  float shi = bti[t] - mi[t] * sci;
  float cbiv = cbi[t];
  for (int r = 0; r < 8; ++r){
    int row = r0 + r;
    float4 xv = ((const float4*)x)[row * 256 + t];
    U4 xb; xb.x = f2bf(xv.x); xb.y = f2bf(xv.y); xb.z = f2bf(xv.z); xb.w = f2bf(xv.w);
    ((U4*)xbf)[row * 256 + t] = xb;
    float h = xv.x*cwov.x + xv.y*cwov.y + xv.z*cwov.z + xv.w*cwov.w + cbov;
    h = h * sco + sho;
    float u = 0.5f * h * (1.0f + erff(h * 0.70710678118654752f));
    unsigned short uh = f2bf(u);
    uho[row*BNC + t] = uh; ulo[row*BNC + t] = f2bf(u - bf2f(uh));
    h = xv.x*cwiv.x + xv.y*cwiv.y + xv.z*cwiv.z + xv.w*cwiv.w + cbiv;
    h = h * sci + shi;
    u = 0.5f * h * (1.0f + erff(h * 0.70710678118654752f));
    uh = f2bf(u);
    uhi[row*BNC + t] = uh; uli[row*BNC + t] = f2bf(u - bf2f(uh));
  }
}

// ---------------- expand GEMM: L = Uh@Eh + Uh@El + Ul@Eh + eb  (split-bf16) ----------------
__global__ __launch_bounds__(256, 2) void k_expand(
    const unsigned short* __restrict__ uh, const unsigned short* __restrict__ ul,
    const unsigned short* __restrict__ eh, const unsigned short* __restrict__ el,
    const float* __restrict__ eb, float* __restrict__ Lout)
{
  __shared__ char lds[2 * 4 * 8192];
  const int tid = threadIdx.x;
  const int lane = tid & 63, w = tid >> 6;
  const int wr = (w >> 1) * 64, wc = (w & 1) * 64;
  const int col0 = blockIdx.x * 128, row0 = blockIdx.y * 128;
  f32x4 acc[4][4] = {};
  auto stage = [&](int kt, int buf){
    char* b = lds + buf * 32768;
    stage_tile(uh + row0 * BNC + kt * 32, 512, b, tid);
    stage_tile(ul + row0 * BNC + kt * 32, 512, b + 8192, tid);
    stage_tile(eh + col0 * BNC + kt * 32, 512, b + 16384, tid);
    stage_tile(el + col0 * BNC + kt * 32, 512, b + 24576, tid);
  };
  stage(0, 0);
  const int NK = BNC / 32;
  for (int kt = 0; kt < NK; ++kt){
    __syncthreads();
    if (kt + 1 < NK) stage(kt + 1, (kt & 1) ^ 1);
    const char* b = lds + (kt & 1) * 32768;
    short8 ah[4], alo[4], bh[4], bl[4];
    #pragma unroll
    for (int m = 0; m < 4; ++m){
      int ra = wr + m * 16 + (lane & 15);
      int rb = wc + m * 16 + (lane & 15);
      ah[m]  = frag_ld(b,         ra, lane);
      alo[m] = frag_ld(b + 8192,  ra, lane);
      bh[m]  = frag_ld(b + 16384, rb, lane);
      bl[m]  = frag_ld(b + 24576, rb, lane);
    }
    #pragma unroll
    for (int m = 0; m < 4; ++m)
      #pragma unroll
      for (int n = 0; n < 4; ++n){
        acc[m][n] = __builtin_amdgcn_mfma_f32_16x16x32_bf16(ah[m],  bh[n], acc[m][n], 0, 0, 0);
        acc[m][n] = __builtin_amdgcn_mfma_f32_16x16x32_bf16(ah[m],  bl[n], acc[m][n], 0, 0, 0);
        acc[m][n] = __builtin_amdgcn_mfma_f32_16x16x32_bf16(alo[m], bh[n], acc[m][n], 0, 0, 0);
      }
  }
  #pragma unroll
  for (int n = 0; n < 4; ++n){
    int col = col0 + wc + n * 16 + (lane & 15);
    float ebv = eb[col];
    #pragma unroll
    for (int m = 0; m < 4; ++m){
      int row = row0 + wr + m * 16 + ((lane >> 4) << 2);
      #pragma unroll
      for (int r = 0; r < 4; ++r)
        Lout[(row + r) * CDIM + col] = acc[m][n][r] + ebv;
    }
  }
}

// ---------------- softmax + top-128 threshold + sparse score ----------------
template<bool WRITE_XS>
__global__ __launch_bounds__(256) void k_select(
    const float* __restrict__ Lg, const float* __restrict__ x,
    unsigned short* __restrict__ obf)
{
  const int lane = threadIdx.x & 63;
  const int row = blockIdx.x * 4 + (threadIdx.x >> 6);
  const float* Lr = Lg + row * CDIM;
  float v[16];
  #pragma unroll
  for (int c = 0; c < 4; ++c){
    float4 t4 = ((const float4*)Lr)[c * 64 + lane];
    v[c*4+0] = t4.x; v[c*4+1] = t4.y; v[c*4+2] = t4.z; v[c*4+3] = t4.w;
  }
  float M = v[0];
  #pragma unroll
  for (int j = 1; j < 16; ++j) M = fmaxf(M, v[j]);
  #pragma unroll
  for (int off = 32; off > 0; off >>= 1) M = fmaxf(M, __shfl_xor(M, off));
  float S = 0.f;
  #pragma unroll
  for (int j = 0; j < 16; ++j) S += expf(v[j] - M);
  #pragma unroll
  for (int off = 32; off > 0; off >>= 1) S += __shfl_xor(S, off);
  unsigned kx[16];
  #pragma unroll
  for (int j = 0; j < 16; ++j){
    union { float f; unsigned u; } q; q.f = v[j];
    kx[j] = q.u ^ ((q.u & 0x80000000u) ? 0xFFFFFFFFu : 0x80000000u);
  }
  unsigned pref = 0;
  for (int bit = 31; bit >= 0; --bit){
    unsigned cand = pref | (1u << bit);
    int c = 0;
    #pragma unroll
    for (int j = 0; j < 16; ++j) c += (kx[j] >= cand) ? 1 : 0;
    #pragma unroll
    for (int off = 32; off > 0; off >>= 1) c += __shfl_xor(c, off);
    if (c >= TOPK) pref = cand;
  }
  float invS = 1.0f / S;
  #pragma unroll
  for (int c = 0; c < 4; ++c){
    U4 o;
    float sc[4];
    #pragma unroll
    for (int j = 0; j < 4; ++j){
      int jj = c*4 + j;
      sc[j] = (kx[jj] >= pref) ? expf(v[jj] - M) * invS : 0.f;
    }
    if (WRITE_XS){
      float4 xv = ((const float4*)(x + row * CDIM))[c * 64 + lane];
      o.x = f2bf(xv.x * sc[0]); o.y = f2bf(xv.y * sc[1]);
      o.z = f2bf(xv.z * sc[2]); o.w = f2bf(xv.w * sc[3]);
    } else {
      o.x = f2bf(sc[0]); o.y = f2bf(sc[1]); o.z = f2bf(sc[2]); o.w = f2bf(sc[3]);
    }
    ((U4*)(obf + row * CDIM))[c * 64 + lane] = o;
  }
}

// ---------------- main dual-A GEMM with fused epilogue ----------------
__global__ __launch_bounds__(256, 2) void k_main(
    const unsigned short* __restrict__ xbf, const unsigned short* __restrict__ xsbf,
    const unsigned short* __restrict__ wt,  const unsigned short* __restrict__ sobf,
    const float* __restrict__ bias, float* __restrict__ out)
{
  __shared__ char lds[2 * 3 * 8192];
  const int tid = threadIdx.x;
  const int lane = tid & 63, w = tid >> 6;
  const int wr = (w >> 1) * 64, wc = (w & 1) * 64;
  const int col0 = blockIdx.x * 128, row0 = blockIdx.y * 128;
  f32x4 acc1[4][4] = {}, acc2[4][4] = {};
  auto stage = [&](int kt, int buf){
    char* b = lds + buf * 24576;
    stage_tile(xbf  + row0 * CDIM + kt * 32, 2048, b, tid);
    stage_tile(xsbf + row0 * CDIM + kt * 32, 2048, b + 8192, tid);
    stage_tile(wt   + col0 * CDIM + kt * 32, 2048, b + 16384, tid);
  };
  stage(0, 0);
  const int NK = CDIM / 32;
  for (int kt = 0; kt < NK; ++kt){
    __syncthreads();
    if (kt + 1 < NK) stage(kt + 1, (kt & 1) ^ 1);
    const char* b = lds + (kt & 1) * 24576;
    short8 a1[4], a2[4], bb[4];
    #pragma unroll
    for (int m = 0; m < 4; ++m){
      int ra = wr + m * 16 + (lane & 15);
      int rb = wc + m * 16 + (lane & 15);
      a1[m] = frag_ld(b,         ra, lane);
      a2[m] = frag_ld(b + 8192,  ra, lane);
      bb[m] = frag_ld(b + 16384, rb, lane);
    }
    #pragma unroll
    for (int m = 0; m < 4; ++m)
      #pragma unroll
      for (int n = 0; n < 4; ++n){
        acc1[m][n] = __builtin_amdgcn_mfma_f32_16x16x32_bf16(a1[m], bb[n], acc1[m][n], 0, 0, 0);
        acc2[m][n] = __builtin_amdgcn_mfma_f32_16x16x32_bf16(a2[m], bb[n], acc2[m][n], 0, 0, 0);
      }
  }
  #pragma unroll
  for (int n = 0; n < 4; ++n){
    int col = col0 + wc + n * 16 + (lane & 15);
    float bv = bias[col];
    #pragma unroll
    for (int m = 0; m < 4; ++m){
      int row = row0 + wr + m * 16 + ((lane >> 4) << 2);
      #pragma unroll
      for (int r = 0; r < 4; ++r){
        float so = bf2f(sobf[(row + r) * CDIM + col]);
        out[(row + r) * CDIM + col] = acc1[m][n][r] * so + acc2[m][n][r] + bv;
      }
    }
  }
}

extern "C" void kernel_launch(void* const* d_in, const int* in_sizes, int n_in,
                              void* d_out, int out_size, void* d_ws, size_t ws_size,
                              hipStream_t stream)
{
  const float* x    = (const float*)d_in[0];
  const float* W    = (const float*)d_in[1];
  const float* bias = (const float*)d_in[2];
  const float* cwo  = (const float*)d_in[3];
  const float* cbo  = (const float*)d_in[4];
  const float* bngo = (const float*)d_in[5];
  const float* bnbo = (const float*)d_in[6];
  const float* bnmo = (const float*)d_in[7];
  const float* bnvo = (const float*)d_in[8];
  const float* ewo  = (const float*)d_in[9];
  const float* ebo  = (const float*)d_in[10];
  const float* cwi  = (const float*)d_in[11];
  const float* cbi  = (const float*)d_in[12];
  const float* bngi = (const float*)d_in[13];
  const float* bnbi = (const float*)d_in[14];
  const float* bnmi = (const float*)d_in[15];
  const float* bnvi = (const float*)d_in[16];
  const float* ewi  = (const float*)d_in[17];
  const float* ebi  = (const float*)d_in[18];
  float* out = (float*)d_out;
  (void)in_sizes; (void)n_in; (void)out_size; (void)ws_size;

  char* ws = (char*)d_ws;
  size_t off = 0;
  auto alloc = [&](size_t bytes){ void* p = ws + off; off += (bytes + 255) & ~(size_t)255; return p; };
  unsigned short* xbf  = (unsigned short*)alloc((size_t)NROWS * CDIM * 2);
  unsigned short* xsbf = (unsigned short*)alloc((size_t)NROWS * CDIM * 2);
  unsigned short* sobf = (unsigned short*)alloc((size_t)NROWS * CDIM * 2);
  float*          Lbuf = (float*)         alloc((size_t)NROWS * CDIM * 4);
  unsigned short* uho  = (unsigned short*)alloc((size_t)NROWS * BNC * 2);
  unsigned short* ulo  = (unsigned short*)alloc((size_t)NROWS * BNC * 2);
  unsigned short* uhi  = (unsigned short*)alloc((size_t)NROWS * BNC * 2);
  unsigned short* uli  = (unsigned short*)alloc((size_t)NROWS * BNC * 2);
  unsigned short* wtb  = (unsigned short*)alloc((size_t)CDIM * CDIM * 2);
  unsigned short* ewho = (unsigned short*)alloc((size_t)CDIM * BNC * 2);
  unsigned short* ewlo = (unsigned short*)alloc((size_t)CDIM * BNC * 2);
  unsigned short* ewhi = (unsigned short*)alloc((size_t)CDIM * BNC * 2);
  unsigned short* ewli = (unsigned short*)alloc((size_t)CDIM * BNC * 2);

  k_wt<<<dim3(32, 32), dim3(32, 8), 0, stream>>>(W, wtb);
  k_split<<<dim3(1024), dim3(256), 0, stream>>>(ewo, ewho, ewlo, CDIM * BNC);
  k_split<<<dim3(1024), dim3(256), 0, stream>>>(ewi, ewhi, ewli, CDIM * BNC);
  k_bottleneck<<<dim3(NROWS / 8), dim3(256), 0, stream>>>(
      x, cwo, cbo, bngo, bnbo, bnmo, bnvo,
      cwi, cbi, bngi, bnbi, bnmi, bnvi, xbf, uho, ulo, uhi, uli);
  k_expand<<<dim3(8, 256), dim3(256), 0, stream>>>(uho, ulo, ewho, ewlo, ebo, Lbuf);
  k_select<false><<<dim3(NROWS / 4), dim3(256), 0, stream>>>(Lbuf, nullptr, sobf);
  k_expand<<<dim3(8, 256), dim3(256), 0, stream>>>(uhi, uli, ewhi, ewli, ebi, Lbuf);
  k_select<true><<<dim3(NROWS / 4), dim3(256), 0, stream>>>(Lbuf, x, xsbf);
  k_main<<<dim3(8, 256), dim3(256), 0, stream>>>(xbf, xsbf, wtb, sobf, bias, out);
}